// Round 1
// baseline (426.479 us; speedup 1.0000x reference)
//
#include <hip/hip_runtime.h>

// Problem constants
#define S_LEN 4096
#define DMODEL 768
#define NHEAD 12
#define HDIM 64
#define DQKV 2304

typedef __attribute__((ext_vector_type(8))) __bf16 bf16x8;
typedef __attribute__((ext_vector_type(4))) float f32x4;
typedef __attribute__((ext_vector_type(8))) unsigned short ushort8;

static __device__ __forceinline__ unsigned short f2bf(float f) {
  unsigned int u = __float_as_uint(f);
  u += 0x7FFFu + ((u >> 16) & 1u);  // round-to-nearest-even
  return (unsigned short)(u >> 16);
}

// ---------------------------------------------------------------------------
// fp32 -> bf16 elementwise convert (n must be multiple of 8)
// ---------------------------------------------------------------------------
__global__ __launch_bounds__(256) void k_convert(const float* __restrict__ in,
                                                 unsigned short* __restrict__ out,
                                                 int n) {
  int i = (blockIdx.x * 256 + threadIdx.x) * 8;
  if (i >= n) return;
  const float4* p = reinterpret_cast<const float4*>(in + i);
  float4 a = p[0], b = p[1];
  ushort8 r;
  r[0] = f2bf(a.x); r[1] = f2bf(a.y); r[2] = f2bf(a.z); r[3] = f2bf(a.w);
  r[4] = f2bf(b.x); r[5] = f2bf(b.y); r[6] = f2bf(b.z); r[7] = f2bf(b.w);
  *reinterpret_cast<ushort8*>(out + i) = r;
}

// ---------------------------------------------------------------------------
// [K][N] fp32  ->  [N][K] bf16 transpose-convert, 64x64 tiles
// ---------------------------------------------------------------------------
__global__ __launch_bounds__(256) void k_transpose(const float* __restrict__ in,
                                                   unsigned short* __restrict__ out,
                                                   int Kdim, int Ndim) {
  __shared__ unsigned short t[64 * 65];
  int k0 = blockIdx.y * 64, n0 = blockIdx.x * 64;
  int tid = threadIdx.x;
#pragma unroll
  for (int p = 0; p < 4; ++p) {
    int r = p * 16 + (tid >> 4);   // k offset in tile
    int c = (tid & 15) * 4;        // n offset in tile
    float4 v = *reinterpret_cast<const float4*>(in + (size_t)(k0 + r) * Ndim + n0 + c);
    t[(c + 0) * 65 + r] = f2bf(v.x);
    t[(c + 1) * 65 + r] = f2bf(v.y);
    t[(c + 2) * 65 + r] = f2bf(v.z);
    t[(c + 3) * 65 + r] = f2bf(v.w);
  }
  __syncthreads();
#pragma unroll
  for (int p = 0; p < 2; ++p) {
    int task = p * 256 + tid;
    int rr = task >> 3;        // n offset
    int cc = (task & 7) * 8;   // k offset
    ushort8 r;
#pragma unroll
    for (int j = 0; j < 8; ++j) r[j] = t[rr * 65 + cc + j];
    *reinterpret_cast<ushort8*>(out + (size_t)(n0 + rr) * Kdim + k0 + cc) = r;
  }
}

// ---------------------------------------------------------------------------
// bf16 MFMA GEMM: C[M=4096][N] = A[M][768] * Bt[N][768]^T
// 128x128 block tile, BK=32, 4 waves, 4x4 16x16x32 frags per wave.
// MODE 0: QKV epilogue (scatter to Q[h][s][d]*0.125, K[h][s][d], Vt[h][d][s])
// MODE 1: proj epilogue (fp32 out + bias)
// ---------------------------------------------------------------------------
template <int MODE>
__global__ __launch_bounds__(256) void k_gemm(const unsigned short* __restrict__ A,
                                              const unsigned short* __restrict__ Bt,
                                              const float* __restrict__ bias,
                                              unsigned short* __restrict__ Qb,
                                              unsigned short* __restrict__ Kb,
                                              unsigned short* __restrict__ Vt,
                                              float* __restrict__ outf) {
  constexpr int KDIM = DMODEL;       // 768
  constexpr int LDSW = 40;           // 32 + 8 pad (80B stride: 2-way bank alias = free)
  __shared__ unsigned short As[128 * LDSW];
  __shared__ unsigned short Bs[128 * LDSW];

  int tid = threadIdx.x;
  int lane = tid & 63, wave = tid >> 6;
  int wr = wave >> 1, wc = wave & 1;         // wave -> 64x64 subtile
  int m0 = blockIdx.y * 128, n0 = blockIdx.x * 128;
  int r16 = lane & 15, g = lane >> 4;

  f32x4 acc[4][4] = {};

  for (int k0 = 0; k0 < KDIM; k0 += 32) {
#pragma unroll
    for (int p = 0; p < 2; ++p) {
      int task = p * 256 + tid;
      int row = task >> 2, seg = (task & 3) * 8;
      ushort8 va = *reinterpret_cast<const ushort8*>(A + (size_t)(m0 + row) * KDIM + k0 + seg);
      *reinterpret_cast<ushort8*>(&As[row * LDSW + seg]) = va;
      ushort8 vb = *reinterpret_cast<const ushort8*>(Bt + (size_t)(n0 + row) * KDIM + k0 + seg);
      *reinterpret_cast<ushort8*>(&Bs[row * LDSW + seg]) = vb;
    }
    __syncthreads();

    bf16x8 af[4], bfr[4];
#pragma unroll
    for (int m = 0; m < 4; ++m)
      af[m] = *reinterpret_cast<const bf16x8*>(&As[(wr * 64 + m * 16 + r16) * LDSW + g * 8]);
#pragma unroll
    for (int n = 0; n < 4; ++n)
      bfr[n] = *reinterpret_cast<const bf16x8*>(&Bs[(wc * 64 + n * 16 + r16) * LDSW + g * 8]);
#pragma unroll
    for (int m = 0; m < 4; ++m)
#pragma unroll
      for (int n = 0; n < 4; ++n)
        acc[m][n] = __builtin_amdgcn_mfma_f32_16x16x32_bf16(af[m], bfr[n], acc[m][n], 0, 0, 0);
    __syncthreads();
  }

  // Epilogue. C/D frag layout: col = lane&15, row = 4*(lane>>4) + reg  [HW-verified]
#pragma unroll
  for (int m = 0; m < 4; ++m) {
    int grow0 = m0 + wr * 64 + m * 16 + 4 * g;  // s index base (4 consecutive)
#pragma unroll
    for (int n = 0; n < 4; ++n) {
      int gcol = n0 + wc * 64 + n * 16 + r16;
      float bv = bias[gcol];
      if (MODE == 0) {
        int sect = gcol / DMODEL;        // uniform per block (768 = 6*128)
        int rem = gcol - sect * DMODEL;
        int h = rem >> 6, hd = rem & 63;
        if (sect == 2) {
          // V transposed: Vt[h][hd][s]; 4 consecutive s -> one 8B store
          ushort4 pk;
          pk.x = f2bf(acc[m][n][0] + bv);
          pk.y = f2bf(acc[m][n][1] + bv);
          pk.z = f2bf(acc[m][n][2] + bv);
          pk.w = f2bf(acc[m][n][3] + bv);
          *reinterpret_cast<ushort4*>(Vt + (size_t)(h * HDIM + hd) * S_LEN + grow0) = pk;
        } else {
          unsigned short* dst = (sect == 0) ? Qb : Kb;
          float sc = (sect == 0) ? 0.125f : 1.0f;  // fold 1/sqrt(64) into Q
#pragma unroll
          for (int i = 0; i < 4; ++i)
            dst[((size_t)h * S_LEN + grow0 + i) * HDIM + hd] = f2bf((acc[m][n][i] + bv) * sc);
        }
      } else {
#pragma unroll
        for (int i = 0; i < 4; ++i)
          outf[(size_t)(grow0 + i) * DMODEL + gcol] = acc[m][n][i] + bv;
      }
    }
  }
}

// ---------------------------------------------------------------------------
// Flash attention: grid (S/64, NHEAD), 4 waves; each wave owns 16 q-rows,
// iterates KV in 64-key tiles with online softmax. P goes through XOR-swizzled
// LDS to convert C/D layout -> A-fragment layout.
// ---------------------------------------------------------------------------
__global__ __launch_bounds__(256) void k_attn(const unsigned short* __restrict__ Q,
                                              const unsigned short* __restrict__ K,
                                              const unsigned short* __restrict__ Vt,
                                              unsigned short* __restrict__ O) {
  __shared__ unsigned short P[4 * 16 * 64];
  int tid = threadIdx.x;
  int lane = tid & 63, wave = tid >> 6;
  int r16 = lane & 15, g = lane >> 4;
  int h = blockIdx.y;
  int qbase = blockIdx.x * 64 + wave * 16;

  // Q fragments (held in registers for whole KV loop); Q is pre-scaled by 0.125
  const unsigned short* qptr = Q + ((size_t)h * S_LEN + qbase + r16) * HDIM + g * 8;
  bf16x8 qf0 = *reinterpret_cast<const bf16x8*>(qptr);
  bf16x8 qf1 = *reinterpret_cast<const bf16x8*>(qptr + 32);

  f32x4 oacc[4] = {};
  float mrow[4] = {-1e30f, -1e30f, -1e30f, -1e30f};
  float lrow[4] = {0.f, 0.f, 0.f, 0.f};
  unsigned short* Pw = &P[wave * 16 * 64];

  for (int kv0 = 0; kv0 < S_LEN; kv0 += 64) {
    // ---- QK^T : S_tile [16 q x 64 keys] ----
    f32x4 s[4];
#pragma unroll
    for (int j = 0; j < 4; ++j) {
      const unsigned short* kptr = K + ((size_t)h * S_LEN + kv0 + j * 16 + r16) * HDIM + g * 8;
      bf16x8 kb0 = *reinterpret_cast<const bf16x8*>(kptr);
      bf16x8 kb1 = *reinterpret_cast<const bf16x8*>(kptr + 32);
      f32x4 z = {};
      z = __builtin_amdgcn_mfma_f32_16x16x32_bf16(qf0, kb0, z, 0, 0, 0);
      s[j] = __builtin_amdgcn_mfma_f32_16x16x32_bf16(qf1, kb1, z, 0, 0, 0);
    }
    // ---- online softmax (row r = 4*g + i, cols spread over 16 lanes x 4 j) ----
    float mnew[4], alpha[4];
#pragma unroll
    for (int i = 0; i < 4; ++i) {
      float mx = fmaxf(fmaxf(s[0][i], s[1][i]), fmaxf(s[2][i], s[3][i]));
#pragma unroll
      for (int d = 1; d < 16; d <<= 1) mx = fmaxf(mx, __shfl_xor(mx, d));
      mnew[i] = fmaxf(mrow[i], mx);
      alpha[i] = __expf(mrow[i] - mnew[i]);
      mrow[i] = mnew[i];
    }
    float pv[4][4];
#pragma unroll
    for (int i = 0; i < 4; ++i) {
      float sum = 0.f;
#pragma unroll
      for (int j = 0; j < 4; ++j) {
        float e = __expf(s[j][i] - mnew[i]);
        pv[j][i] = e;
        sum += e;
      }
#pragma unroll
      for (int d = 1; d < 16; d <<= 1) sum += __shfl_xor(sum, d);
      lrow[i] = lrow[i] * alpha[i] + sum;
      oacc[0][i] *= alpha[i];
      oacc[1][i] *= alpha[i];
      oacc[2][i] *= alpha[i];
      oacc[3][i] *= alpha[i];
    }
    // ---- P -> LDS (bf16, XOR-swizzled to kill b128 read conflicts) ----
#pragma unroll
    for (int j = 0; j < 4; ++j) {
      int c = j * 16 + r16;
#pragma unroll
      for (int i = 0; i < 4; ++i) {
        int r = 4 * g + i;
        int e = (c & 7) | ((((c >> 3) ^ (r & 7)) & 7) << 3);
        Pw[r * 64 + e] = f2bf(pv[j][i]);
      }
    }
    __syncthreads();
    // ---- PV : A = P [16 q x 64 key], B = V^T fragments ----
    bf16x8 pa[2];
#pragma unroll
    for (int kk = 0; kk < 2; ++kk) {
      int b8 = (kk * 4 + g) ^ (r16 & 7);
      pa[kk] = *reinterpret_cast<const bf16x8*>(&Pw[r16 * 64 + b8 * 8]);
    }
#pragma unroll
    for (int j = 0; j < 4; ++j) {
      const unsigned short* vp = Vt + (size_t)(h * HDIM + j * 16 + r16) * S_LEN + kv0 + g * 8;
      bf16x8 vb0 = *reinterpret_cast<const bf16x8*>(vp);
      bf16x8 vb1 = *reinterpret_cast<const bf16x8*>(vp + 32);
      oacc[j] = __builtin_amdgcn_mfma_f32_16x16x32_bf16(pa[0], vb0, oacc[j], 0, 0, 0);
      oacc[j] = __builtin_amdgcn_mfma_f32_16x16x32_bf16(pa[1], vb1, oacc[j], 0, 0, 0);
    }
    __syncthreads();
  }
  // ---- write O[s][h*64+d] bf16 ----
#pragma unroll
  for (int j = 0; j < 4; ++j) {
    int col = h * HDIM + j * 16 + r16;
#pragma unroll
    for (int i = 0; i < 4; ++i) {
      int srow = qbase + 4 * g + i;
      O[(size_t)srow * DMODEL + col] = f2bf(oacc[j][i] / lrow[i]);
    }
  }
}

// ---------------------------------------------------------------------------
extern "C" void kernel_launch(void* const* d_in, const int* in_sizes, int n_in,
                              void* d_out, int out_size, void* d_ws, size_t ws_size,
                              hipStream_t stream) {
  const float* x = (const float*)d_in[0];       // [4096][768]
  const float* w_qkv = (const float*)d_in[1];   // [768][2304]
  const float* b_qkv = (const float*)d_in[2];   // [2304]
  const float* w_proj = (const float*)d_in[3];  // [768][768]
  const float* b_proj = (const float*)d_in[4];  // [768]
  float* out = (float*)d_out;                   // [4096][768]

  unsigned short* ws16 = (unsigned short*)d_ws;
  unsigned short* xb = ws16;                                   // 4096*768
  unsigned short* wqkvT = xb + (size_t)S_LEN * DMODEL;         // 2304*768
  unsigned short* wprojT = wqkvT + (size_t)DQKV * DMODEL;      // 768*768
  unsigned short* Qb = wprojT + (size_t)DMODEL * DMODEL;       // 12*4096*64
  unsigned short* Kb = Qb + (size_t)NHEAD * S_LEN * HDIM;
  unsigned short* Vt = Kb + (size_t)NHEAD * S_LEN * HDIM;
  unsigned short* Ob = xb;  // alias: x dead after QKV GEMM

  // 1) convert x
  k_convert<<<(S_LEN * DMODEL) / (256 * 8), 256, 0, stream>>>(x, xb, S_LEN * DMODEL);
  // 2) transpose-convert weights to [N][K] bf16
  k_transpose<<<dim3(DQKV / 64, DMODEL / 64), 256, 0, stream>>>(w_qkv, wqkvT, DMODEL, DQKV);
  k_transpose<<<dim3(DMODEL / 64, DMODEL / 64), 256, 0, stream>>>(w_proj, wprojT, DMODEL, DMODEL);
  // 3) QKV GEMM + scatter
  k_gemm<0><<<dim3(DQKV / 128, S_LEN / 128), 256, 0, stream>>>(xb, wqkvT, b_qkv, Qb, Kb, Vt, nullptr);
  // 4) attention
  k_attn<<<dim3(S_LEN / 64, NHEAD), 256, 0, stream>>>(Qb, Kb, Vt, Ob);
  // 5) output projection
  k_gemm<1><<<dim3(DMODEL / 128, S_LEN / 128), 256, 0, stream>>>(Ob, wprojT, b_proj, nullptr, nullptr, nullptr, out);
}

// Round 2
// 416.112 us; speedup vs baseline: 1.0249x; 1.0249x over previous
//
#include <hip/hip_runtime.h>

// Problem constants
#define S_LEN 4096
#define DMODEL 768
#define NHEAD 12
#define HDIM 64
#define DQKV 2304

typedef __attribute__((ext_vector_type(8))) __bf16 bf16x8;
typedef __attribute__((ext_vector_type(4))) float f32x4;
typedef __attribute__((ext_vector_type(8))) unsigned short ushort8;

static __device__ __forceinline__ unsigned short f2bf(float f) {
  unsigned int u = __float_as_uint(f);
  u += 0x7FFFu + ((u >> 16) & 1u);  // round-to-nearest-even
  return (unsigned short)(u >> 16);
}

// ---------------------------------------------------------------------------
// fp32 -> bf16 elementwise convert (n must be multiple of 8)
// ---------------------------------------------------------------------------
__global__ __launch_bounds__(256) void k_convert(const float* __restrict__ in,
                                                 unsigned short* __restrict__ out,
                                                 int n) {
  int i = (blockIdx.x * 256 + threadIdx.x) * 8;
  if (i >= n) return;
  const float4* p = reinterpret_cast<const float4*>(in + i);
  float4 a = p[0], b = p[1];
  ushort8 r;
  r[0] = f2bf(a.x); r[1] = f2bf(a.y); r[2] = f2bf(a.z); r[3] = f2bf(a.w);
  r[4] = f2bf(b.x); r[5] = f2bf(b.y); r[6] = f2bf(b.z); r[7] = f2bf(b.w);
  *reinterpret_cast<ushort8*>(out + i) = r;
}

// ---------------------------------------------------------------------------
// [K][N] fp32  ->  [N][K] bf16 transpose-convert, 64x64 tiles
// ---------------------------------------------------------------------------
__global__ __launch_bounds__(256) void k_transpose(const float* __restrict__ in,
                                                   unsigned short* __restrict__ out,
                                                   int Kdim, int Ndim) {
  __shared__ unsigned short t[64 * 65];
  int k0 = blockIdx.y * 64, n0 = blockIdx.x * 64;
  int tid = threadIdx.x;
#pragma unroll
  for (int p = 0; p < 4; ++p) {
    int r = p * 16 + (tid >> 4);   // k offset in tile
    int c = (tid & 15) * 4;        // n offset in tile
    float4 v = *reinterpret_cast<const float4*>(in + (size_t)(k0 + r) * Ndim + n0 + c);
    t[(c + 0) * 65 + r] = f2bf(v.x);
    t[(c + 1) * 65 + r] = f2bf(v.y);
    t[(c + 2) * 65 + r] = f2bf(v.z);
    t[(c + 3) * 65 + r] = f2bf(v.w);
  }
  __syncthreads();
#pragma unroll
  for (int p = 0; p < 2; ++p) {
    int task = p * 256 + tid;
    int rr = task >> 3;        // n offset
    int cc = (task & 7) * 8;   // k offset
    ushort8 r;
#pragma unroll
    for (int j = 0; j < 8; ++j) r[j] = t[rr * 65 + cc + j];
    *reinterpret_cast<ushort8*>(out + (size_t)(n0 + rr) * Kdim + k0 + cc) = r;
  }
}

// ---------------------------------------------------------------------------
// bf16 MFMA GEMM: C[M=4096][N] = A[M][768] * Bt[N][768]^T
// 128x128 block tile, BK=32, 4 waves, 4x4 16x16x32 frags per wave.
// MODE 0: QKV epilogue (scatter to Q[h][s][d]*0.125, K[h][s][d], Vt[h][d][s])
// MODE 1: proj epilogue (fp32 out + bias)
// ---------------------------------------------------------------------------
template <int MODE>
__global__ __launch_bounds__(256) void k_gemm(const unsigned short* __restrict__ A,
                                              const unsigned short* __restrict__ Bt,
                                              const float* __restrict__ bias,
                                              unsigned short* __restrict__ Qb,
                                              unsigned short* __restrict__ Kb,
                                              unsigned short* __restrict__ Vt,
                                              float* __restrict__ outf) {
  constexpr int KDIM = DMODEL;       // 768
  constexpr int LDSW = 40;           // 32 + 8 pad (80B stride: 2-way bank alias = free)
  __shared__ unsigned short As[128 * LDSW];
  __shared__ unsigned short Bs[128 * LDSW];

  int tid = threadIdx.x;
  int lane = tid & 63, wave = tid >> 6;
  int wr = wave >> 1, wc = wave & 1;         // wave -> 64x64 subtile
  int m0 = blockIdx.y * 128, n0 = blockIdx.x * 128;
  int r16 = lane & 15, g = lane >> 4;

  f32x4 acc[4][4] = {};

  for (int k0 = 0; k0 < KDIM; k0 += 32) {
#pragma unroll
    for (int p = 0; p < 2; ++p) {
      int task = p * 256 + tid;
      int row = task >> 2, seg = (task & 3) * 8;
      ushort8 va = *reinterpret_cast<const ushort8*>(A + (size_t)(m0 + row) * KDIM + k0 + seg);
      *reinterpret_cast<ushort8*>(&As[row * LDSW + seg]) = va;
      ushort8 vb = *reinterpret_cast<const ushort8*>(Bt + (size_t)(n0 + row) * KDIM + k0 + seg);
      *reinterpret_cast<ushort8*>(&Bs[row * LDSW + seg]) = vb;
    }
    __syncthreads();

    bf16x8 af[4], bfr[4];
#pragma unroll
    for (int m = 0; m < 4; ++m)
      af[m] = *reinterpret_cast<const bf16x8*>(&As[(wr * 64 + m * 16 + r16) * LDSW + g * 8]);
#pragma unroll
    for (int n = 0; n < 4; ++n)
      bfr[n] = *reinterpret_cast<const bf16x8*>(&Bs[(wc * 64 + n * 16 + r16) * LDSW + g * 8]);
#pragma unroll
    for (int m = 0; m < 4; ++m)
#pragma unroll
      for (int n = 0; n < 4; ++n)
        acc[m][n] = __builtin_amdgcn_mfma_f32_16x16x32_bf16(af[m], bfr[n], acc[m][n], 0, 0, 0);
    __syncthreads();
  }

  // Epilogue. C/D frag layout: col = lane&15, row = 4*(lane>>4) + reg  [HW-verified]
#pragma unroll
  for (int m = 0; m < 4; ++m) {
    int grow0 = m0 + wr * 64 + m * 16 + 4 * g;  // s index base (4 consecutive)
#pragma unroll
    for (int n = 0; n < 4; ++n) {
      int gcol = n0 + wc * 64 + n * 16 + r16;
      float bv = bias[gcol];
      if (MODE == 0) {
        int sect = gcol / DMODEL;        // uniform per block (768 = 6*128)
        int rem = gcol - sect * DMODEL;
        int h = rem >> 6, hd = rem & 63;
        if (sect == 2) {
          // V transposed: Vt[h][hd][s]; 4 consecutive s -> one 8B store
          ushort4 pk;
          pk.x = f2bf(acc[m][n][0] + bv);
          pk.y = f2bf(acc[m][n][1] + bv);
          pk.z = f2bf(acc[m][n][2] + bv);
          pk.w = f2bf(acc[m][n][3] + bv);
          *reinterpret_cast<ushort4*>(Vt + (size_t)(h * HDIM + hd) * S_LEN + grow0) = pk;
        } else {
          unsigned short* dst = (sect == 0) ? Qb : Kb;
          float sc = (sect == 0) ? 0.125f : 1.0f;  // fold 1/sqrt(64) into Q
#pragma unroll
          for (int i = 0; i < 4; ++i)
            dst[((size_t)h * S_LEN + grow0 + i) * HDIM + hd] = f2bf((acc[m][n][i] + bv) * sc);
        }
      } else {
#pragma unroll
        for (int i = 0; i < 4; ++i)
          outf[(size_t)(grow0 + i) * DMODEL + gcol] = acc[m][n][i] + bv;
      }
    }
  }
}

// ---------------------------------------------------------------------------
// Flash attention, barrier-free, LDS-free.
// grid (S/64, NHEAD), 4 independent waves; each wave owns 16 q-rows.
//
// Swapped QK^T: st = mfma(K_frag, Q_frag) so each lane holds P values for ONE
// q row (q = lane&15).  K rows are loaded PRE-PERMUTED with
//   key(j, m) = 32*(j&1) + 8*(m>>2) + 4*(j>>1) + (m&3)     (bijective on 0..63)
// so that lane (g = lane>>4) ends up holding exactly keys {32*kk + 8g + e},
// i.e. the PV A-fragment is built lane-locally: pa[kk][e] = p[kk+2*(e>>2)][e&3].
// Softmax: per-lane scalar m/l, row-reduce = 2 shuffles (xor16, xor32).
// Only alpha / 1/l cross lanes (4 shuffles) to reach the PV C-layout rows.
// ---------------------------------------------------------------------------
__global__ __launch_bounds__(256, 3) void k_attn(const unsigned short* __restrict__ Q,
                                                 const unsigned short* __restrict__ K,
                                                 const unsigned short* __restrict__ Vt,
                                                 unsigned short* __restrict__ O) {
  constexpr float LOG2E = 1.4426950408889634f;
  int tid = threadIdx.x;
  int lane = tid & 63, wave = tid >> 6;
  int r16 = lane & 15, g = lane >> 4;
  int h = blockIdx.y;
  int qbase = blockIdx.x * 64 + wave * 16;

  const unsigned short* Kh = K + (size_t)h * S_LEN * HDIM;
  const unsigned short* Vh = Vt + (size_t)h * HDIM * S_LEN;

  // Q fragments (B-operand): lane holds Q[qbase+r16][8g..8g+7]; pre-scaled by 0.125
  const unsigned short* qptr = Q + ((size_t)h * S_LEN + qbase + r16) * HDIM + g * 8;
  bf16x8 qf0 = *reinterpret_cast<const bf16x8*>(qptr);
  bf16x8 qf1 = *reinterpret_cast<const bf16x8*>(qptr + 32);

  f32x4 oacc[4] = {};
  float mrow = -1e30f, lrow = 0.f;
  int rowbase = 8 * (r16 >> 2) + (r16 & 3);  // permuted K-row base for this lane

  for (int kv0 = 0; kv0 < S_LEN; kv0 += 64) {
    // ---- QK^T (swapped): st[j] holds P_raw[q=r16][key 32(j&1)+8g+4(j>>1)+i]
    f32x4 s[4];
#pragma unroll
    for (int j = 0; j < 4; ++j) {
      int krow = kv0 + rowbase + 32 * (j & 1) + 4 * (j >> 1);
      const unsigned short* kp = Kh + (size_t)krow * HDIM + g * 8;
      bf16x8 kb0 = *reinterpret_cast<const bf16x8*>(kp);
      bf16x8 kb1 = *reinterpret_cast<const bf16x8*>(kp + 32);
      f32x4 z = {};
      z = __builtin_amdgcn_mfma_f32_16x16x32_bf16(kb0, qf0, z, 0, 0, 0);
      s[j] = __builtin_amdgcn_mfma_f32_16x16x32_bf16(kb1, qf1, z, 0, 0, 0);
    }

    // ---- V loads issued early (hide L2 latency under softmax VALU)
    bf16x8 vb[4][2];
#pragma unroll
    for (int j = 0; j < 4; ++j) {
      const unsigned short* vp = Vh + (size_t)(j * 16 + r16) * S_LEN + kv0 + g * 8;
      vb[j][0] = *reinterpret_cast<const bf16x8*>(vp);
      vb[j][1] = *reinterpret_cast<const bf16x8*>(vp + 32);
    }

    // ---- online softmax, per-lane (q = r16), e-base scores, exp2 with fused log2e
    float mj[4];
#pragma unroll
    for (int j = 0; j < 4; ++j)
      mj[j] = fmaxf(fmaxf(s[j][0], s[j][1]), fmaxf(s[j][2], s[j][3]));
    float mx = fmaxf(fmaxf(mj[0], mj[1]), fmaxf(mj[2], mj[3]));
    mx = fmaxf(mx, __shfl_xor(mx, 16));
    mx = fmaxf(mx, __shfl_xor(mx, 32));
    float mnew = fmaxf(mrow, mx);
    float al = exp2f((mrow - mnew) * LOG2E);
    float mC = mnew * LOG2E;
    mrow = mnew;

    float p[4][4];
    float sum = 0.f;
#pragma unroll
    for (int j = 0; j < 4; ++j) {
      float s0 = 0.f;
#pragma unroll
      for (int i = 0; i < 4; ++i) {
        float e = exp2f(__builtin_fmaf(s[j][i], LOG2E, -mC));
        p[j][i] = e;
        s0 += e;
      }
      sum += s0;
    }
    sum += __shfl_xor(sum, 16);
    sum += __shfl_xor(sum, 32);
    lrow = lrow * al + sum;

    // ---- redistribute alpha to PV C-layout rows (q = 4g+i) and rescale O
#pragma unroll
    for (int i = 0; i < 4; ++i) {
      float av = __shfl(al, 20 * g + i);
      oacc[0][i] *= av;
      oacc[1][i] *= av;
      oacc[2][i] *= av;
      oacc[3][i] *= av;
    }

    // ---- lane-local P -> bf16 A-fragments: pa[kk][e] = p[kk + 2*(e>>2)][e&3]
    ushort8 pk0, pk1;
#pragma unroll
    for (int e = 0; e < 8; ++e) {
      pk0[e] = f2bf(p[2 * (e >> 2)][e & 3]);
      pk1[e] = f2bf(p[1 + 2 * (e >> 2)][e & 3]);
    }
    bf16x8 pa0 = __builtin_bit_cast(bf16x8, pk0);
    bf16x8 pa1 = __builtin_bit_cast(bf16x8, pk1);

    // ---- PV
#pragma unroll
    for (int j = 0; j < 4; ++j) {
      oacc[j] = __builtin_amdgcn_mfma_f32_16x16x32_bf16(pa0, vb[j][0], oacc[j], 0, 0, 0);
      oacc[j] = __builtin_amdgcn_mfma_f32_16x16x32_bf16(pa1, vb[j][1], oacc[j], 0, 0, 0);
    }
  }

  // ---- epilogue: O[s][h*64+d] bf16, rows q = 4g+i need 1/l from lane 4g+i
#pragma unroll
  for (int i = 0; i < 4; ++i) {
    float linv = 1.0f / __shfl(lrow, 20 * g + i);
    int srow = qbase + 4 * g + i;
#pragma unroll
    for (int j = 0; j < 4; ++j) {
      int col = h * HDIM + j * 16 + r16;
      O[(size_t)srow * DMODEL + col] = f2bf(oacc[j][i] * linv);
    }
  }
}

// ---------------------------------------------------------------------------
extern "C" void kernel_launch(void* const* d_in, const int* in_sizes, int n_in,
                              void* d_out, int out_size, void* d_ws, size_t ws_size,
                              hipStream_t stream) {
  const float* x = (const float*)d_in[0];       // [4096][768]
  const float* w_qkv = (const float*)d_in[1];   // [768][2304]
  const float* b_qkv = (const float*)d_in[2];   // [2304]
  const float* w_proj = (const float*)d_in[3];  // [768][768]
  const float* b_proj = (const float*)d_in[4];  // [768]
  float* out = (float*)d_out;                   // [4096][768]

  unsigned short* ws16 = (unsigned short*)d_ws;
  unsigned short* xb = ws16;                                   // 4096*768
  unsigned short* wqkvT = xb + (size_t)S_LEN * DMODEL;         // 2304*768
  unsigned short* wprojT = wqkvT + (size_t)DQKV * DMODEL;      // 768*768
  unsigned short* Qb = wprojT + (size_t)DMODEL * DMODEL;       // 12*4096*64
  unsigned short* Kb = Qb + (size_t)NHEAD * S_LEN * HDIM;
  unsigned short* Vt = Kb + (size_t)NHEAD * S_LEN * HDIM;
  unsigned short* Ob = xb;  // alias: x dead after QKV GEMM

  // 1) convert x
  k_convert<<<(S_LEN * DMODEL) / (256 * 8), 256, 0, stream>>>(x, xb, S_LEN * DMODEL);
  // 2) transpose-convert weights to [N][K] bf16
  k_transpose<<<dim3(DQKV / 64, DMODEL / 64), 256, 0, stream>>>(w_qkv, wqkvT, DMODEL, DQKV);
  k_transpose<<<dim3(DMODEL / 64, DMODEL / 64), 256, 0, stream>>>(w_proj, wprojT, DMODEL, DMODEL);
  // 3) QKV GEMM + scatter
  k_gemm<0><<<dim3(DQKV / 128, S_LEN / 128), 256, 0, stream>>>(xb, wqkvT, b_qkv, Qb, Kb, Vt, nullptr);
  // 4) attention
  k_attn<<<dim3(S_LEN / 64, NHEAD), 256, 0, stream>>>(Qb, Kb, Vt, Ob);
  // 5) output projection
  k_gemm<1><<<dim3(DMODEL / 128, S_LEN / 128), 256, 0, stream>>>(Ob, wprojT, b_proj, nullptr, nullptr, nullptr, out);
}